// Round 4
// baseline (246.569 us; speedup 1.0000x reference)
//
#include <hip/hip_runtime.h>
#include <math.h>

// Problem constants: token shape (b=16, c=16, n=25, h=16, w=128)
#define SB 819200   // batch stride = c*n*h*w
#define SC 51200    // c stride    = n*h*w
#define SN 2048     // n stride    = h*w
#define CH 256      // c*h  (t dim)
#define NW 3200     // n*w  (k dim of gemm1, s dim of gemm2)
#define NPARTS 5
#define PARTLEN 640         // 3200 / 5 = 10 chunks of 64
#define SPART 1048576       // 16*256*256 floats per split-K partial

typedef __bf16 bf16x8 __attribute__((ext_vector_type(8)));
typedef __bf16 bf16x4 __attribute__((ext_vector_type(4)));
typedef float  f32x4  __attribute__((ext_vector_type(4)));

__device__ __forceinline__ bf16x8 cvt8(float4 a, float4 b) {
    bf16x8 r;
    r[0] = (__bf16)a.x; r[1] = (__bf16)a.y; r[2] = (__bf16)a.z; r[3] = (__bf16)a.w;
    r[4] = (__bf16)b.x; r[5] = (__bf16)b.y; r[6] = (__bf16)b.z; r[7] = (__bf16)b.w;
    return r;
}

// ---------------------------------------------------------------------------
// Kernel 1: inverse L2 norms of Q rows and K rows. One wave per (b,t) row,
// shfl-xor reduction (no LDS tree). grid 1024 x 256 (4 waves/block).
// ---------------------------------------------------------------------------
__global__ __launch_bounds__(256) void norms_kernel(const float* __restrict__ q,
                                                    const float* __restrict__ k,
                                                    float* __restrict__ inv_nq,
                                                    float* __restrict__ inv_nk) {
    const int wave = threadIdx.x >> 6;
    const int lane = threadIdx.x & 63;
    const int row = blockIdx.x * 4 + wave;   // b*256 + t
    const int b = row >> 8;
    const int t = row & 255;
    const size_t base = (size_t)b * SB + (size_t)(t >> 4) * SC +
                        (size_t)(t & 15) * 128 + lane * 2;
    float sq = 0.f, sk = 0.f;
#pragma unroll
    for (int nch = 0; nch < 25; nch++) {
        const float2 a = *(const float2*)(q + base + (size_t)nch * SN);
        const float2 c = *(const float2*)(k + base + (size_t)nch * SN);
        sq += a.x * a.x + a.y * a.y;
        sk += c.x * c.x + c.y * c.y;
    }
#pragma unroll
    for (int off = 32; off; off >>= 1) {
        sq += __shfl_xor(sq, off, 64);
        sk += __shfl_xor(sk, off, 64);
    }
    if (lane == 0) {
        inv_nq[row] = 1.0f / fmaxf(sqrtf(sq), 1e-12f);
        inv_nk[row] = 1.0f / fmaxf(sqrtf(sk), 1e-12f);
    }
}

// ---------------------------------------------------------------------------
// Kernel 2: split-K bf16-MFMA GEMM for unnormalized scores.
// Spart[p][b][t][r] = sum_{k in part p} Q[t][k]*K[r][k]   (fp32 out)
// Block = 128x128 tile, 4 waves of 64x64 (4x4 C-tiles of 16x16x32).
// grid (3 causal 128-tiles, 5 parts, 16 b) = 240 blocks.
// Partials land in d_out used as scratch (5 * 4 MB <= 52 MB).
// ---------------------------------------------------------------------------
__global__ __launch_bounds__(256, 2) void gemm1_kernel(const float* __restrict__ q,
                                                       const float* __restrict__ k,
                                                       float* __restrict__ Sp) {
    __shared__ alignas(16) __bf16 As[128 * 72];
    __shared__ alignas(16) __bf16 Bs[128 * 72];

    const int tid = threadIdx.x;
    const int b = blockIdx.z;
    const int part = blockIdx.y;
    const int tile = blockIdx.x;           // 0:(0,0) 1:(1,0) 2:(1,1)
    const int tm = (tile + 1) >> 1;
    const int tn = tile >> 1;

    const int lane = tid & 63;
    const int wave = tid >> 6;
    const int wm = wave >> 1;              // wave m-half (64)
    const int wn = wave & 1;               // wave n-half (64)

    // staging coords: thread covers row = tid>>1, 32 floats at col (tid&1)*32
    const int srow = tid >> 1;
    const int scol = (tid & 1) * 32;
    const int ta = tm * 128 + srow;
    const int rb = tn * 128 + srow;
    const float* qrow = q + (size_t)b * SB + (size_t)(ta >> 4) * SC + (size_t)(ta & 15) * 128;
    const float* krow = k + (size_t)b * SB + (size_t)(rb >> 4) * SC + (size_t)(rb & 15) * 128;

    f32x4 acc[4][4] = {};
    bool live[4][4];
#pragma unroll
    for (int mi = 0; mi < 4; mi++)
#pragma unroll
        for (int ni = 0; ni < 4; ni++)
            live[mi][ni] = (tn * 128 + wn * 64 + ni * 16) <= (tm * 128 + wm * 64 + mi * 16);

    for (int ch = 0; ch < 10; ch++) {
        const int kg = part * PARTLEN + ch * 64;            // multiple of 64
        const size_t koff = (size_t)(kg >> 7) * SN + (kg & 127) + scol;

        float4 av[8], bv[8];
#pragma unroll
        for (int j = 0; j < 8; j++) {
            av[j] = *(const float4*)(qrow + koff + j * 4);
            bv[j] = *(const float4*)(krow + koff + j * 4);
        }
        __syncthreads();   // previous iteration's LDS reads done
#pragma unroll
        for (int j = 0; j < 4; j++) {
            *(bf16x8*)&As[srow * 72 + scol + j * 8] = cvt8(av[2 * j], av[2 * j + 1]);
            *(bf16x8*)&Bs[srow * 72 + scol + j * 8] = cvt8(bv[2 * j], bv[2 * j + 1]);
        }
        __syncthreads();
#pragma unroll
        for (int ks = 0; ks < 2; ks++) {
            const int ko = ks * 32 + (lane >> 4) * 8;
            bf16x8 af[4], bf[4];
#pragma unroll
            for (int mi = 0; mi < 4; mi++)
                af[mi] = *(const bf16x8*)&As[(wm * 64 + mi * 16 + (lane & 15)) * 72 + ko];
#pragma unroll
            for (int ni = 0; ni < 4; ni++)
                bf[ni] = *(const bf16x8*)&Bs[(wn * 64 + ni * 16 + (lane & 15)) * 72 + ko];
#pragma unroll
            for (int mi = 0; mi < 4; mi++)
#pragma unroll
                for (int ni = 0; ni < 4; ni++)
                    if (live[mi][ni])
                        acc[mi][ni] = __builtin_amdgcn_mfma_f32_16x16x32_bf16(
                            af[mi], bf[ni], acc[mi][ni], 0, 0, 0);
        }
    }

    float* o = Sp + (size_t)part * SPART + (size_t)b * 65536;
#pragma unroll
    for (int mi = 0; mi < 4; mi++)
#pragma unroll
        for (int ni = 0; ni < 4; ni++) {
            if (!live[mi][ni]) continue;
            const int r = tn * 128 + wn * 64 + ni * 16 + (lane & 15);
#pragma unroll
            for (int j = 0; j < 4; j++) {
                const int t = tm * 128 + wm * 64 + mi * 16 + (lane >> 4) * 4 + j;
                o[(size_t)t * 256 + r] = acc[mi][ni][j];
            }
        }
}

// ---------------------------------------------------------------------------
// Kernel 3: sum split-K partials, apply inverse norms, causal mask, softmax,
// write P as bf16. One wave per (b,t) row; lane covers r = lane*4..+3.
// grid (64, 16), 256 threads.
// ---------------------------------------------------------------------------
__global__ __launch_bounds__(256) void softmax_kernel(const float* __restrict__ Sp,
                                                      const float* __restrict__ inv_nq,
                                                      const float* __restrict__ inv_nk,
                                                      __bf16* __restrict__ P) {
    const int wave = threadIdx.x >> 6;
    const int lane = threadIdx.x & 63;
    const int t = blockIdx.x * 4 + wave;
    const int b = blockIdx.y;
    const size_t rowbase = ((size_t)b * 256 + t) * 256;
    const int r0 = lane * 4;

    float4 s4 = {0.f, 0.f, 0.f, 0.f};
#pragma unroll
    for (int p = 0; p < NPARTS; p++) {
        const float4 x = *(const float4*)(Sp + (size_t)p * SPART + rowbase + r0);
        s4.x += x.x; s4.y += x.y; s4.z += x.z; s4.w += x.w;
    }
    const float qn = inv_nq[b * 256 + t];
    const float4 kn = *(const float4*)(inv_nk + b * 256 + r0);

    float val[4] = {s4.x * qn * kn.x, s4.y * qn * kn.y,
                    s4.z * qn * kn.z, s4.w * qn * kn.w};
    float m = -1e30f;
#pragma unroll
    for (int j = 0; j < 4; j++) {
        if (r0 + j > t) val[j] = -1e30f;
        m = fmaxf(m, val[j]);
    }
#pragma unroll
    for (int off = 32; off; off >>= 1) m = fmaxf(m, __shfl_xor(m, off, 64));

    float e[4], sum = 0.f;
#pragma unroll
    for (int j = 0; j < 4; j++) {
        e[j] = (r0 + j <= t) ? expf(val[j] - m) : 0.f;
        sum += e[j];
    }
#pragma unroll
    for (int off = 32; off; off >>= 1) sum += __shfl_xor(sum, off, 64);

    const float inv = 1.0f / sum;
    bf16x4 o;
    o[0] = (__bf16)(e[0] * inv);
    o[1] = (__bf16)(e[1] * inv);
    o[2] = (__bf16)(e[2] * inv);
    o[3] = (__bf16)(e[3] * inv);
    *(bf16x4*)(P + rowbase + r0) = o;
}

// ---------------------------------------------------------------------------
// Kernel 4: O[t][s] = sum_r P[t][r]*V[r][s] + V[t][s], bf16 MFMA.
// Block = 128 t x 128 s (one n), K = 256 r in 4 chunks of 64.
// Epilogue: two 64-row passes through a fp32 LDS tile [64][132] so the
// buffer-add + store are fully float4-coalesced (fixes round-3 stride bug:
// the 128-wide tile needs stride >=128; 68 aliased rows).
// grid (25 n, 2 t-tiles, 16 b) = 800 blocks.
// ---------------------------------------------------------------------------
__global__ __launch_bounds__(256, 4) void gemm2_kernel(const __bf16* __restrict__ P,
                                                       const float* __restrict__ v,
                                                       float* __restrict__ out) {
    __shared__ alignas(16) char smem[36864];
    __bf16* Ps = (__bf16*)smem;                // [128][72]  (18432 B)
    __bf16* Vs = (__bf16*)(smem + 18432);      // [128][72]  (18432 B)
    float* Es = (float*)smem;                  // [64][132]  epilogue reuse (33792 B)

    const int tid = threadIdx.x;
    const int b = blockIdx.z;
    const int tt = blockIdx.y;
    const int n = blockIdx.x;

    const int lane = tid & 63;
    const int wave = tid >> 6;
    const int wm = wave >> 1;
    const int wn = wave & 1;

    // P staging: row = tid>>1, 32 bf16 at col (tid&1)*32
    const int prow = tid >> 1;
    const int pcol = (tid & 1) * 32;
    const __bf16* Prow = P + ((size_t)b * 256 + tt * 128 + prow) * 256;

    // V staging: w-group u = tid&7 (16 floats), r base = (tid>>3) (0..31)
    const int vu = tid & 7;
    const int vr = tid >> 3;
    const float* vbase = v + (size_t)b * SB + (size_t)n * SN;

    f32x4 acc[4][4] = {};

    for (int kc = 0; kc < 4; kc++) {
        bf16x8 p4[4];
#pragma unroll
        for (int j = 0; j < 4; j++)
            p4[j] = *(const bf16x8*)(Prow + kc * 64 + pcol + j * 8);

        float4 vv[2][4];
#pragma unroll
        for (int g = 0; g < 2; g++) {
            const int rg = kc * 64 + vr + g * 32;
            const float* vrow = vbase + (size_t)(rg >> 4) * SC + (size_t)(rg & 15) * 128;
#pragma unroll
            for (int jj = 0; jj < 4; jj++)
                vv[g][jj] = *(const float4*)(vrow + vu * 16 + jj * 4);
        }
        __syncthreads();
#pragma unroll
        for (int j = 0; j < 4; j++)
            *(bf16x8*)&Ps[prow * 72 + pcol + j * 8] = p4[j];
#pragma unroll
        for (int g = 0; g < 2; g++) {
            const int rl = vr + g * 32;              // r-local 0..63
            const int rsw = rl ^ (vu << 3);          // XOR swizzle keyed on s>>4 (=vu)
#pragma unroll
            for (int jj = 0; jj < 4; jj++) {
                const float* f = (const float*)&vv[g][jj];
#pragma unroll
                for (int e = 0; e < 4; e++) {
                    const int s = vu * 16 + jj * 4 + e;
                    Vs[s * 72 + rsw] = (__bf16)f[e];
                }
            }
        }
        __syncthreads();
#pragma unroll
        for (int ks = 0; ks < 2; ks++) {
            const int ko = ks * 32 + (lane >> 4) * 8;
            bf16x8 af[4], bf[4];
#pragma unroll
            for (int mi = 0; mi < 4; mi++)
                af[mi] = *(const bf16x8*)&Ps[(wm * 64 + mi * 16 + (lane & 15)) * 72 + ko];
#pragma unroll
            for (int ni = 0; ni < 4; ni++) {
                const int s0 = wn * 64 + ni * 16;
                const int sw = ((s0 >> 4) & 7) << 3;
                bf[ni] = *(const bf16x8*)&Vs[(s0 + (lane & 15)) * 72 + (ko ^ sw)];
            }
#pragma unroll
            for (int mi = 0; mi < 4; mi++)
#pragma unroll
                for (int ni = 0; ni < 4; ni++)
                    acc[mi][ni] = __builtin_amdgcn_mfma_f32_16x16x32_bf16(
                        af[mi], bf[ni], acc[mi][ni], 0, 0, 0);
        }
        __syncthreads();   // all waves done with LDS this iter
    }

    // ---- epilogue: two 64-row passes (waves wm==half own those rows)
    for (int half = 0; half < 2; half++) {
        if (half == 1) __syncthreads();     // previous pass's Es reads done
        if (wm == half) {
#pragma unroll
            for (int mi = 0; mi < 4; mi++)
#pragma unroll
                for (int ni = 0; ni < 4; ni++)
#pragma unroll
                    for (int j = 0; j < 4; j++) {
                        const int trow = mi * 16 + (lane >> 4) * 4 + j;   // 0..63
                        const int wcol = wn * 64 + ni * 16 + (lane & 15); // 0..127
                        Es[trow * 132 + wcol] = acc[mi][ni][j];
                    }
        }
        __syncthreads();
#pragma unroll
        for (int it = 0; it < 8; it++) {
            const int tl = it * 8 + (tid >> 5);       // 0..63
            const int w4 = (tid & 31) * 4;            // 0..124
            const int t = tt * 128 + half * 64 + tl;
            const size_t a = (size_t)b * SB + (size_t)(t >> 4) * SC + (size_t)n * SN +
                             (size_t)(t & 15) * 128 + w4;
            float4 r4 = *(const float4*)&Es[tl * 132 + w4];
            const float4 buf = *(const float4*)(v + a);
            r4.x += buf.x; r4.y += buf.y; r4.z += buf.z; r4.w += buf.w;
            *(float4*)(out + a) = r4;
        }
    }
}

// ---------------------------------------------------------------------------
extern "C" void kernel_launch(void* const* d_in, const int* in_sizes, int n_in,
                              void* d_out, int out_size, void* d_ws, size_t ws_size,
                              hipStream_t stream) {
    const float* q = (const float*)d_in[0];
    const float* k = (const float*)d_in[1];
    const float* v = (const float*)d_in[2];
    float* out = (float*)d_out;

    float* ws = (float*)d_ws;
    float* inv_nq = ws;                        // 4096 floats
    float* inv_nk = ws + 4096;                 // 4096 floats
    __bf16* P = (__bf16*)(ws + 8192);          // 16*256*256 bf16 = 2 MB

    // d_out doubles as split-K scratch (5 * 4 MB = 21 MB <= 52 MB out),
    // fully overwritten by gemm2 afterwards.
    float* Spart = out;

    norms_kernel<<<dim3(1024), dim3(256), 0, stream>>>(q, k, inv_nq, inv_nk);
    gemm1_kernel<<<dim3(3, NPARTS, 16), dim3(256), 0, stream>>>(q, k, Spart);
    softmax_kernel<<<dim3(64, 16), dim3(256), 0, stream>>>(Spart, inv_nq, inv_nk, P);
    gemm2_kernel<<<dim3(25, 2, 16), dim3(256), 0, stream>>>(P, v, out);
}

// Round 5
// 227.199 us; speedup vs baseline: 1.0853x; 1.0853x over previous
//
#include <hip/hip_runtime.h>
#include <math.h>

// Problem constants: token shape (b=16, c=16, n=25, h=16, w=128)
#define SB 819200   // batch stride = c*n*h*w
#define SC 51200    // c stride    = n*h*w
#define SN 2048     // n stride    = h*w
#define CH 256      // c*h  (t dim)
#define NW 3200     // n*w  (k dim of gemm1, s dim of gemm2)
#define NPARTS 5
#define PARTLEN 640         // 3200 / 5 = 10 chunks of 64
#define SPART 1048576       // 16*256*256 floats per split-K partial
#define G1BLOCKS 240        // 3 tiles * 5 parts * 16 b

typedef __bf16 bf16x8 __attribute__((ext_vector_type(8)));
typedef __bf16 bf16x4 __attribute__((ext_vector_type(4)));
typedef __bf16 bf16x2 __attribute__((ext_vector_type(2)));
typedef float  f32x4  __attribute__((ext_vector_type(4)));

__device__ __forceinline__ bf16x8 cvt8(float4 a, float4 b) {
    bf16x8 r;
    r[0] = (__bf16)a.x; r[1] = (__bf16)a.y; r[2] = (__bf16)a.z; r[3] = (__bf16)a.w;
    r[4] = (__bf16)b.x; r[5] = (__bf16)b.y; r[6] = (__bf16)b.z; r[7] = (__bf16)b.w;
    return r;
}

// ---------------------------------------------------------------------------
// Fat kernel: blocks [0, 240) = split-K bf16-MFMA score GEMM;
//             blocks [240, 1264) = inverse L2 norms (independent work, fused
//             so its HBM reads overlap the latency-bound GEMM tiles).
// GEMM part: Spart[p][b][t][r] = sum_{k in part p} Q[t][k]*K[r][k], fp32,
// 128x128 tile, 4 waves of 64x64 (4x4 C-tiles of 16x16x32), causal 3-tile.
// ---------------------------------------------------------------------------
__global__ __launch_bounds__(256, 2) void gemm1_norms_kernel(const float* __restrict__ q,
                                                             const float* __restrict__ k,
                                                             float* __restrict__ Sp,
                                                             float* __restrict__ inv_nq,
                                                             float* __restrict__ inv_nk) {
    __shared__ alignas(16) __bf16 As[128 * 72];
    __shared__ alignas(16) __bf16 Bs[128 * 72];

    const int tid = threadIdx.x;
    const int lane = tid & 63;
    const int wave = tid >> 6;

    if (blockIdx.x >= G1BLOCKS) {
        // ---- norms part: one wave per (b,t) row, shfl-xor reduction
        const int row = (blockIdx.x - G1BLOCKS) * 4 + wave;   // 0..4095
        const int b = row >> 8;
        const int t = row & 255;
        const size_t base = (size_t)b * SB + (size_t)(t >> 4) * SC +
                            (size_t)(t & 15) * 128 + lane * 2;
        float sq = 0.f, sk = 0.f;
#pragma unroll
        for (int nch = 0; nch < 25; nch++) {
            const float2 a = *(const float2*)(q + base + (size_t)nch * SN);
            const float2 c = *(const float2*)(k + base + (size_t)nch * SN);
            sq += a.x * a.x + a.y * a.y;
            sk += c.x * c.x + c.y * c.y;
        }
#pragma unroll
        for (int off = 32; off; off >>= 1) {
            sq += __shfl_xor(sq, off, 64);
            sk += __shfl_xor(sk, off, 64);
        }
        if (lane == 0) {
            inv_nq[row] = 1.0f / fmaxf(sqrtf(sq), 1e-12f);
            inv_nk[row] = 1.0f / fmaxf(sqrtf(sk), 1e-12f);
        }
        return;
    }

    // ---- GEMM part
    const int bx = blockIdx.x;
    const int tile = bx % 3;               // 0:(0,0) 1:(1,0) 2:(1,1)
    const int part = (bx / 3) % NPARTS;
    const int b = bx / (3 * NPARTS);
    const int tm = (tile + 1) >> 1;
    const int tn = tile >> 1;

    const int wm = wave >> 1;              // wave m-half (64)
    const int wn = wave & 1;               // wave n-half (64)

    // staging coords: thread covers row = tid>>1, 32 floats at col (tid&1)*32
    const int srow = tid >> 1;
    const int scol = (tid & 1) * 32;
    const int ta = tm * 128 + srow;
    const int rb = tn * 128 + srow;
    const float* qrow = q + (size_t)b * SB + (size_t)(ta >> 4) * SC + (size_t)(ta & 15) * 128;
    const float* krow = k + (size_t)b * SB + (size_t)(rb >> 4) * SC + (size_t)(rb & 15) * 128;

    f32x4 acc[4][4] = {};
    bool live[4][4];
#pragma unroll
    for (int mi = 0; mi < 4; mi++)
#pragma unroll
        for (int ni = 0; ni < 4; ni++)
            live[mi][ni] = (tn * 128 + wn * 64 + ni * 16) <= (tm * 128 + wm * 64 + mi * 16);

    for (int ch = 0; ch < 10; ch++) {
        const int kg = part * PARTLEN + ch * 64;            // multiple of 64
        const size_t koff = (size_t)(kg >> 7) * SN + (kg & 127) + scol;

        float4 av[8], bv[8];
#pragma unroll
        for (int j = 0; j < 8; j++) {
            av[j] = *(const float4*)(qrow + koff + j * 4);
            bv[j] = *(const float4*)(krow + koff + j * 4);
        }
        __syncthreads();   // previous iteration's LDS reads done
#pragma unroll
        for (int j = 0; j < 4; j++) {
            *(bf16x8*)&As[srow * 72 + scol + j * 8] = cvt8(av[2 * j], av[2 * j + 1]);
            *(bf16x8*)&Bs[srow * 72 + scol + j * 8] = cvt8(bv[2 * j], bv[2 * j + 1]);
        }
        __syncthreads();
#pragma unroll
        for (int ks = 0; ks < 2; ks++) {
            const int ko = ks * 32 + (lane >> 4) * 8;
            bf16x8 af[4], bf[4];
#pragma unroll
            for (int mi = 0; mi < 4; mi++)
                af[mi] = *(const bf16x8*)&As[(wm * 64 + mi * 16 + (lane & 15)) * 72 + ko];
#pragma unroll
            for (int ni = 0; ni < 4; ni++)
                bf[ni] = *(const bf16x8*)&Bs[(wn * 64 + ni * 16 + (lane & 15)) * 72 + ko];
#pragma unroll
            for (int mi = 0; mi < 4; mi++)
#pragma unroll
                for (int ni = 0; ni < 4; ni++)
                    if (live[mi][ni])
                        acc[mi][ni] = __builtin_amdgcn_mfma_f32_16x16x32_bf16(
                            af[mi], bf[ni], acc[mi][ni], 0, 0, 0);
        }
    }

    float* o = Sp + (size_t)part * SPART + (size_t)b * 65536;
#pragma unroll
    for (int mi = 0; mi < 4; mi++)
#pragma unroll
        for (int ni = 0; ni < 4; ni++) {
            if (!live[mi][ni]) continue;
            const int r = tn * 128 + wn * 64 + ni * 16 + (lane & 15);
#pragma unroll
            for (int j = 0; j < 4; j++) {
                const int t = tm * 128 + wm * 64 + mi * 16 + (lane >> 4) * 4 + j;
                o[(size_t)t * 256 + r] = acc[mi][ni][j];
            }
        }
}

// ---------------------------------------------------------------------------
// Kernel 2: sum split-K partials, apply inverse norms, causal mask, softmax,
// write P as bf16. One wave per (b,t) row; lane covers r = lane*4..+3.
// ---------------------------------------------------------------------------
__global__ __launch_bounds__(256) void softmax_kernel(const float* __restrict__ Sp,
                                                      const float* __restrict__ inv_nq,
                                                      const float* __restrict__ inv_nk,
                                                      __bf16* __restrict__ P) {
    const int wave = threadIdx.x >> 6;
    const int lane = threadIdx.x & 63;
    const int t = blockIdx.x * 4 + wave;
    const int b = blockIdx.y;
    const size_t rowbase = ((size_t)b * 256 + t) * 256;
    const int r0 = lane * 4;

    float4 s4 = {0.f, 0.f, 0.f, 0.f};
#pragma unroll
    for (int p = 0; p < NPARTS; p++) {
        const float4 x = *(const float4*)(Sp + (size_t)p * SPART + rowbase + r0);
        s4.x += x.x; s4.y += x.y; s4.z += x.z; s4.w += x.w;
    }
    const float qn = inv_nq[b * 256 + t];
    const float4 kn = *(const float4*)(inv_nk + b * 256 + r0);

    float val[4] = {s4.x * qn * kn.x, s4.y * qn * kn.y,
                    s4.z * qn * kn.z, s4.w * qn * kn.w};
    float m = -1e30f;
#pragma unroll
    for (int j = 0; j < 4; j++) {
        if (r0 + j > t) val[j] = -1e30f;
        m = fmaxf(m, val[j]);
    }
#pragma unroll
    for (int off = 32; off; off >>= 1) m = fmaxf(m, __shfl_xor(m, off, 64));

    float e[4], sum = 0.f;
#pragma unroll
    for (int j = 0; j < 4; j++) {
        e[j] = (r0 + j <= t) ? expf(val[j] - m) : 0.f;
        sum += e[j];
    }
#pragma unroll
    for (int off = 32; off; off >>= 1) sum += __shfl_xor(sum, off, 64);

    const float inv = 1.0f / sum;
    bf16x4 o;
    o[0] = (__bf16)(e[0] * inv);
    o[1] = (__bf16)(e[1] * inv);
    o[2] = (__bf16)(e[2] * inv);
    o[3] = (__bf16)(e[3] * inv);
    *(bf16x4*)(P + rowbase + r0) = o;
}

// ---------------------------------------------------------------------------
// Kernel 3: O[t][s] = sum_r P[t][r]*V[r][s] + V[t][s], bf16 MFMA.
// Block = 128 t x 64 s (half of one n), K = 256 r in 4 chunks of 64.
// P A-fragments load DIRECTLY from global (natural [t][r] layout == A-frag
// layout; P is 2 MB, L2-hot). Only V goes through LDS (transposed, paired-row
// b32 stores, XOR swizzle). grid (50 nw, 2 t-tiles, 16 b) = 1600 blocks.
// ---------------------------------------------------------------------------
__global__ __launch_bounds__(256, 4) void gemm2_kernel(const __bf16* __restrict__ P,
                                                       const float* __restrict__ v,
                                                       float* __restrict__ out) {
    __shared__ alignas(16) char smem[9216];
    __bf16* Vs = (__bf16*)smem;     // [64 s][72 r-stride]  (9216 B)
    float* Es = (float*)smem;       // [32][68] epilogue reuse (8704 B)

    const int tid = threadIdx.x;
    const int b = blockIdx.z;
    const int tt = blockIdx.y;      // 0..1 (t 128-half)
    const int nw = blockIdx.x;      // 0..49
    const int n = nw >> 1;
    const int whalf = nw & 1;

    const int lane = tid & 63;
    const int wave = tid >> 6;
    const int wm = wave >> 1;       // t 64-half within 128-tile
    const int wn = wave & 1;        // s 32-half within 64-tile
    const int l15 = lane & 15;
    const int quad = lane >> 4;

    // V staging coords: thread covers s-group vu*8..+7, row pair 2rp, 2rp+1
    const int vu = tid & 7;
    const int rp = tid >> 3;        // 0..31
    const float* vbase = v + (size_t)b * SB + (size_t)n * SN + whalf * 64;

    // P A-frag base: row = tt*128 + wm*64 + mi*16 + l15, col = kc*64+ks*32+quad*8
    const __bf16* Pbase = P + ((size_t)b * 256 + tt * 128 + wm * 64 + l15) * 256 + quad * 8;

    f32x4 acc[4][2] = {};

    for (int kc = 0; kc < 4; kc++) {
        // A fragments direct from global (issued early, L2-hot)
        bf16x8 af[4][2];
#pragma unroll
        for (int mi = 0; mi < 4; mi++)
#pragma unroll
            for (int ks = 0; ks < 2; ks++)
                af[mi][ks] = *(const bf16x8*)(Pbase + (size_t)mi * 16 * 256 + kc * 64 + ks * 32);

        // V loads: rows 2rp, 2rp+1 of this r-chunk, 8 floats each
        float vr0[8], vr1[8];
        {
            const int r0 = kc * 64 + 2 * rp;
            const int r1 = r0 + 1;
            const float* row0 = vbase + (size_t)(r0 >> 4) * SC + (size_t)(r0 & 15) * 128;
            const float* row1 = vbase + (size_t)(r1 >> 4) * SC + (size_t)(r1 & 15) * 128;
            *(float4*)&vr0[0] = *(const float4*)(row0 + vu * 8);
            *(float4*)&vr0[4] = *(const float4*)(row0 + vu * 8 + 4);
            *(float4*)&vr1[0] = *(const float4*)(row1 + vu * 8);
            *(float4*)&vr1[4] = *(const float4*)(row1 + vu * 8 + 4);
        }
        __syncthreads();   // prior Vs reads (or Es init) done
        {
            const int rl0 = 2 * rp;
#pragma unroll
            for (int sj = 0; sj < 8; sj++) {
                const int s = vu * 8 + sj;
                bf16x2 pr;
                pr[0] = (__bf16)vr0[sj];
                pr[1] = (__bf16)vr1[sj];
                *(bf16x2*)&Vs[s * 72 + (rl0 ^ (s & 0x38))] = pr;
            }
        }
        __syncthreads();
#pragma unroll
        for (int ks = 0; ks < 2; ks++) {
            bf16x8 bfr[2];
#pragma unroll
            for (int ni = 0; ni < 2; ni++) {
                const int s = wn * 32 + ni * 16 + l15;
                bfr[ni] = *(const bf16x8*)&Vs[s * 72 + ((ks * 32 + quad * 8) ^ (s & 0x38))];
            }
#pragma unroll
            for (int mi = 0; mi < 4; mi++)
#pragma unroll
                for (int ni = 0; ni < 2; ni++)
                    acc[mi][ni] = __builtin_amdgcn_mfma_f32_16x16x32_bf16(
                        af[mi][ks], bfr[ni], acc[mi][ni], 0, 0, 0);
        }
    }

    // ---- epilogue: 4 passes of 32 t-rows through Es[32][68], coalesced out
    for (int p = 0; p < 4; p++) {
        __syncthreads();   // prior Vs/Es reads done
        if (wm == (p >> 1)) {
            const int mibase = (p & 1) * 2;
#pragma unroll
            for (int mm = 0; mm < 2; mm++)
#pragma unroll
                for (int ni = 0; ni < 2; ni++) {
                    const f32x4 a = acc[mibase + mm][ni];
                    const int wcol = wn * 32 + ni * 16 + l15;
#pragma unroll
                    for (int j = 0; j < 4; j++)
                        Es[(mm * 16 + quad * 4 + j) * 68 + wcol] = a[j];
                }
        }
        __syncthreads();
#pragma unroll
        for (int it = 0; it < 2; it++) {
            const int tl = it * 16 + (tid >> 4);      // 0..31
            const int w4 = (tid & 15) * 4;            // 0..60
            const int t = tt * 128 + p * 32 + tl;
            const size_t a = (size_t)b * SB + (size_t)(t >> 4) * SC + (size_t)n * SN +
                             (size_t)(t & 15) * 128 + whalf * 64 + w4;
            float4 r4 = *(const float4*)&Es[tl * 68 + w4];
            const float4 buf = *(const float4*)(v + a);
            r4.x += buf.x; r4.y += buf.y; r4.z += buf.z; r4.w += buf.w;
            *(float4*)(out + a) = r4;
        }
    }
}

// ---------------------------------------------------------------------------
extern "C" void kernel_launch(void* const* d_in, const int* in_sizes, int n_in,
                              void* d_out, int out_size, void* d_ws, size_t ws_size,
                              hipStream_t stream) {
    const float* q = (const float*)d_in[0];
    const float* k = (const float*)d_in[1];
    const float* v = (const float*)d_in[2];
    float* out = (float*)d_out;

    float* ws = (float*)d_ws;
    float* inv_nq = ws;                        // 4096 floats
    float* inv_nk = ws + 4096;                 // 4096 floats
    __bf16* P = (__bf16*)(ws + 8192);          // 16*256*256 bf16 = 2 MB

    // d_out doubles as split-K scratch (5 * 4 MB = 21 MB <= 52 MB out),
    // fully overwritten by gemm2 afterwards.
    float* Spart = out;

    // blocks [0,240) GEMM, [240,1264) norms (1024 blocks * 4 rows)
    gemm1_norms_kernel<<<dim3(G1BLOCKS + 1024), dim3(256), 0, stream>>>(
        q, k, Spart, inv_nq, inv_nk);
    softmax_kernel<<<dim3(64, 16), dim3(256), 0, stream>>>(Spart, inv_nq, inv_nk, P);
    gemm2_kernel<<<dim3(50, 2, 16), dim3(256), 0, stream>>>(P, v, out);
}